// Round 4
// baseline (1277.972 us; speedup 1.0000x reference)
//
#include <hip/hip_runtime.h>
#include <hip/hip_bf16.h>

typedef __attribute__((ext_vector_type(8))) __bf16 bf16x8;
typedef __attribute__((ext_vector_type(4))) float f32x4;
typedef __attribute__((ext_vector_type(8))) float f32x8;

static __device__ __forceinline__ unsigned short bf16r(float f) {
  unsigned u = __builtin_bit_cast(unsigned, f);
  return (unsigned short)((u + 0x7FFFu + ((u >> 16) & 1u)) >> 16);
}

// tanh(x) = 1 - 2/(exp2(x*2*log2e)+1); saturates correctly for |x| large.
static __device__ __forceinline__ float ftanh(float x) {
  float e = __builtin_amdgcn_exp2f(x * 2.8853900817779268f);
  return 1.0f - 2.0f * __builtin_amdgcn_rcpf(e + 1.0f);
}

// global->LDS direct copy, 16B per lane (dest = wave-uniform base + lane*16)
static __device__ __forceinline__ void gload_lds16(const void* g, void* l) {
  __builtin_amdgcn_global_load_lds(
      (const __attribute__((address_space(1))) unsigned int*)g,
      (__attribute__((address_space(3))) unsigned int*)l, 16, 0, 0);
}

// ---------------- prologue: pack weights (bf16, frag order) + params --------
// ws layout (bytes):
//   w1pk: [0, 131072)          8 mtiles x 16 ksteps x 64 lanes x 8 bf16 (pi-permuted k)
//   w2pk: [131072, 163840)     8 mtiles x 4 ksteps x 64 lanes x 8 bf16 (pi-permuted k)
//   w3pk: [163840, 196608)     same as w2pk
//   ppk : [196608, 200192)     7 params x [q=4][32] f32
// (R12 pack: slot (q,j) of kstep s <-> col = s*32 + (j>>2)*16 + q*4 + (j&3))
__global__ void pack_kernel(const float* __restrict__ w1, const float* __restrict__ w2,
                            const float* __restrict__ w3, const float* __restrict__ b1,
                            const float* __restrict__ g1, const float* __restrict__ be1,
                            const float* __restrict__ b2, const float* __restrict__ g2,
                            const float* __restrict__ be2, const float* __restrict__ b3,
                            unsigned short* __restrict__ w1pk, unsigned short* __restrict__ w2pk,
                            unsigned short* __restrict__ w3pk, float* __restrict__ ppk) {
  int idx = blockIdx.x * 256 + threadIdx.x;
  if (idx < 65536) {            // w1, pi-permuted k-order
    int j = idx & 7, l = (idx >> 3) & 63, s = (idx >> 9) & 15, t = idx >> 13;
    int row = t * 16 + (l & 15);
    int col = s * 32 + (j >> 2) * 16 + (l >> 4) * 4 + (j & 3);
    w1pk[idx] = bf16r(w1[row * 512 + col]);
  } else if (idx < 81920) {     // w2, pi-permuted k-order
    int i = idx - 65536;
    int j = i & 7, l = (i >> 3) & 63, s = (i >> 9) & 3, t = i >> 11;
    int row = t * 16 + (l & 15);
    int col = (2 * s + (j >> 2)) * 16 + (l >> 4) * 4 + (j & 3);
    w2pk[i] = bf16r(w2[row * 128 + col]);
  } else if (idx < 98304) {     // w3, pi-permuted k-order
    int i = idx - 81920;
    int j = i & 7, l = (i >> 3) & 63, s = (i >> 9) & 3, t = i >> 11;
    int row = t * 16 + (l & 15);
    int col = (2 * s + (j >> 2)) * 16 + (l >> 4) * 4 + (j & 3);
    w3pk[i] = bf16r(w3[row * 128 + col]);
  } else if (idx < 99200) {     // params: b1,g1,be1,b2,g2,be2,b3
    int i = idx - 98304;        // 0..895
    int p = i >> 7;
    int r = i & 127;
    int qq = r >> 5, ii = r & 31;
    int m = (ii >> 2) * 16 + qq * 4 + (ii & 3);
    const float* src = (p == 0) ? b1 : (p == 1) ? g1 : (p == 2) ? be1
                     : (p == 3) ? b2 : (p == 4) ? g2 : (p == 5) ? be2 : b3;
    ppk[i] = src[m];
  }
}

// ---------------- fused backbone: persistent 4-chunk, deep prefetch --------
// R15. Post-mortems R12(null)/R13(-10%)/R14(-5%) kill the read-pattern theory
// family: bytes and request shape are fine. New theory: PHASE OSCILLATION.
// All blocks run in lockstep rounds (1 block/CU, equal durations); each round
// = 21us read-burst + ~10us read-SILENT tail (epilogues/GEMM2/3/stores) + w1
// refill. Chip-wide duty cycle ~60% -> 188us vs 110us roofline.
// Fix: (a) 512 blocks x 512thr, each owns 4 chunks of 128 rows -> w1 filled
// once, 1 barrier total, 3 of 4 chunk boundaries are barrier-free;
// (b) 2 waves/SIMD (256-reg budget; occupancy was perf-null R3-R10) funds a
// 4-deep batch pipeline st[4][4] (64 VGPR); (c) last 4 issue slots of chunk c
// load chunk c+1's batches 0..3 -> the tail runs with 16 next-chunk reads in
// flight. Predicted 150-170us; null would exonerate phase-dead-time too.
__global__ __launch_bounds__(512)
__attribute__((amdgpu_waves_per_eu(2, 2)))
void backbone_main(const float* __restrict__ obs,
                   const unsigned char* __restrict__ w1pk_g,
                   const bf16x8* __restrict__ w2pk,
                   const bf16x8* __restrict__ w3pk,
                   const float* __restrict__ ppk,
                   float* __restrict__ out) {
  __shared__ __align__(16) unsigned char w1s[131072];

  const int tid  = threadIdx.x;
  const int lane = tid & 63;
  const int wv   = tid >> 6;          // 0..7
  const int q    = lane >> 4;
  const int rl   = lane & 15;
  // block owns 128 consecutive rows per chunk; chunk stride = 512*128 rows.
  const size_t row0 = (size_t)blockIdx.x * 128 + (unsigned)(wv * 16) + (unsigned)rl;
  const size_t CROWS = (size_t)512 * 128;          // 65536 rows per chunk step

  f32x4 st[4][4];
  // lane q owns floats q*4 + {0,16,32,48} of each 2-kstep (64-float) batch.
#define LOAD_BATCH(slot, P, s0)                                                   \
  do {                                                                            \
    st[slot][0] = __builtin_nontemporal_load((const f32x4*)((P) + (s0) * 32));    \
    st[slot][1] = __builtin_nontemporal_load((const f32x4*)((P) + (s0) * 32 + 16));\
    st[slot][2] = __builtin_nontemporal_load((const f32x4*)((P) + (s0) * 32 + 32));\
    st[slot][3] = __builtin_nontemporal_load((const f32x4*)((P) + (s0) * 32 + 48));\
  } while (0)

  // prologue: chunk-0 batches 0..3 (4-deep pipeline primed before LDS fill)
  {
    const float* p00 = obs + row0 * 512 + q * 4;
    LOAD_BATCH(0, p00, 0);
    LOAD_BATCH(1, p00, 2);
    LOAD_BATCH(2, p00, 4);
    LOAD_BATCH(3, p00, 6);
  }

  // fill w1 into LDS once: 16 rounds x (512 threads x 16B) = 128KB
#pragma unroll
  for (int r = 0; r < 16; ++r) {
    gload_lds16(w1pk_g + r * 8192 + tid * 16, w1s + r * 8192 + wv * 1024);
  }
  __syncthreads();   // the only barrier in the kernel

  const bf16x8* w1l = (const bf16x8*)w1s;   // frag (t,s): [(t*16+s)*64 + lane]

#pragma unroll 1
  for (int c = 0; c < 4; ++c) {
    const size_t brow = row0 + (size_t)c * CROWS;
    const float* pc  = obs + brow * 512 + q * 4;          // this chunk
    const float* pcn = pc + CROWS * 512;                  // next chunk

    f32x4 acc[8];
#pragma unroll
    for (int t = 0; t < 8; ++t) acc[t] = (f32x4){0.f, 0.f, 0.f, 0.f};

    // ---- GEMM1: K=512, 8 batches, 4 in flight; slots bb>=4 prefetch c+1 ----
#pragma unroll
    for (int bb = 0; bb < 8; ++bb) {
      f32x4 a0 = st[bb & 3][0], a1 = st[bb & 3][1];
      f32x4 a2 = st[bb & 3][2], a3 = st[bb & 3][3];
      if (bb < 4) {
        LOAD_BATCH(bb & 3, pc, 2 * (bb + 4));
      } else if (c < 3) {
        LOAD_BATCH(bb & 3, pcn, 2 * (bb - 4));
      }
      f32x8 r0 = {a0.x, a0.y, a0.z, a0.w, a1.x, a1.y, a1.z, a1.w};
      f32x8 r1 = {a2.x, a2.y, a2.z, a2.w, a3.x, a3.y, a3.z, a3.w};
      bf16x8 b0 = __builtin_convertvector(r0, bf16x8);
      bf16x8 b1 = __builtin_convertvector(r1, bf16x8);
#pragma unroll
      for (int t = 0; t < 8; ++t) {
        bf16x8 af0 = w1l[(t * 16 + 2 * bb) * 64 + lane];
        acc[t] = __builtin_amdgcn_mfma_f32_16x16x32_bf16(af0, b0, acc[t], 0, 0, 0);
      }
#pragma unroll
      for (int t = 0; t < 8; ++t) {
        bf16x8 af1 = w1l[(t * 16 + 2 * bb + 1) * 64 + lane];
        acc[t] = __builtin_amdgcn_mfma_f32_16x16x32_bf16(af1, b1, acc[t], 0, 0, 0);
      }
    }

    bf16x8 pkv[4];

    // ---- epilogue 1: +b1, LayerNorm(g1,be1), tanh, pack bf16 ----
    {
      const float* pb = ppk + 0 * 128 + q * 32;
      const float* pg = ppk + 1 * 128 + q * 32;
      const float* pe = ppk + 2 * 128 + q * 32;
      float s1 = 0.f, s2 = 0.f;
#pragma unroll
      for (int t = 0; t < 8; ++t) {
        f32x4 bb = *(const f32x4*)(pb + t * 4);
        f32x4 v = acc[t];
        v.x += bb.x; v.y += bb.y; v.z += bb.z; v.w += bb.w;
        acc[t] = v;
        s1 += (v.x + v.y) + (v.z + v.w);
        s2 += (v.x * v.x + v.y * v.y) + (v.z * v.z + v.w * v.w);
      }
      s1 += __shfl_xor(s1, 16, 64);
      s1 += __shfl_xor(s1, 32, 64);
      s2 += __shfl_xor(s2, 16, 64);
      s2 += __shfl_xor(s2, 32, 64);
      float mu  = s1 * (1.0f / 128.0f);
      float var = s2 * (1.0f / 128.0f) - mu * mu;
      float rs  = __builtin_amdgcn_rsqf(var + 1e-5f);
#pragma unroll
      for (int t2 = 0; t2 < 4; ++t2) {
        f32x4 ga = *(const f32x4*)(pg + (2 * t2) * 4);
        f32x4 gb = *(const f32x4*)(pg + (2 * t2 + 1) * 4);
        f32x4 ea = *(const f32x4*)(pe + (2 * t2) * 4);
        f32x4 eb = *(const f32x4*)(pe + (2 * t2 + 1) * 4);
        f32x4 va = acc[2 * t2];
        f32x4 vb = acc[2 * t2 + 1];
        f32x8 cat = {ftanh((va.x - mu) * rs * ga.x + ea.x),
                     ftanh((va.y - mu) * rs * ga.y + ea.y),
                     ftanh((va.z - mu) * rs * ga.z + ea.z),
                     ftanh((va.w - mu) * rs * ga.w + ea.w),
                     ftanh((vb.x - mu) * rs * gb.x + eb.x),
                     ftanh((vb.y - mu) * rs * gb.y + eb.y),
                     ftanh((vb.z - mu) * rs * gb.z + eb.z),
                     ftanh((vb.w - mu) * rs * gb.w + eb.w)};
        pkv[t2] = __builtin_convertvector(cat, bf16x8);
      }
    }

    // ---- GEMM2: K=128 (4 ksteps), B-frags are the lane's own pkv regs ----
#pragma unroll
    for (int t = 0; t < 8; ++t) acc[t] = (f32x4){0.f, 0.f, 0.f, 0.f};
#pragma unroll
    for (int s = 0; s < 4; ++s) {
#pragma unroll
      for (int t = 0; t < 8; ++t) {
        bf16x8 af = w2pk[(t * 4 + s) * 64 + lane];
        acc[t] = __builtin_amdgcn_mfma_f32_16x16x32_bf16(af, pkv[s], acc[t], 0, 0, 0);
      }
    }

    // ---- epilogue 2: +b2, LayerNorm(g2,be2), tanh, pack ----
    {
      const float* pb = ppk + 3 * 128 + q * 32;
      const float* pg = ppk + 4 * 128 + q * 32;
      const float* pe = ppk + 5 * 128 + q * 32;
      float s1 = 0.f, s2 = 0.f;
#pragma unroll
      for (int t = 0; t < 8; ++t) {
        f32x4 bb = *(const f32x4*)(pb + t * 4);
        f32x4 v = acc[t];
        v.x += bb.x; v.y += bb.y; v.z += bb.z; v.w += bb.w;
        acc[t] = v;
        s1 += (v.x + v.y) + (v.z + v.w);
        s2 += (v.x * v.x + v.y * v.y) + (v.z * v.z + v.w * v.w);
      }
      s1 += __shfl_xor(s1, 16, 64);
      s1 += __shfl_xor(s1, 32, 64);
      s2 += __shfl_xor(s2, 16, 64);
      s2 += __shfl_xor(s2, 32, 64);
      float mu  = s1 * (1.0f / 128.0f);
      float var = s2 * (1.0f / 128.0f) - mu * mu;
      float rs  = __builtin_amdgcn_rsqf(var + 1e-5f);
#pragma unroll
      for (int t2 = 0; t2 < 4; ++t2) {
        f32x4 ga = *(const f32x4*)(pg + (2 * t2) * 4);
        f32x4 gb = *(const f32x4*)(pg + (2 * t2 + 1) * 4);
        f32x4 ea = *(const f32x4*)(pe + (2 * t2) * 4);
        f32x4 eb = *(const f32x4*)(pe + (2 * t2 + 1) * 4);
        f32x4 va = acc[2 * t2];
        f32x4 vb = acc[2 * t2 + 1];
        f32x8 cat = {ftanh((va.x - mu) * rs * ga.x + ea.x),
                     ftanh((va.y - mu) * rs * ga.y + ea.y),
                     ftanh((va.z - mu) * rs * ga.z + ea.z),
                     ftanh((va.w - mu) * rs * ga.w + ea.w),
                     ftanh((vb.x - mu) * rs * gb.x + eb.x),
                     ftanh((vb.y - mu) * rs * gb.y + eb.y),
                     ftanh((vb.z - mu) * rs * gb.z + eb.z),
                     ftanh((vb.w - mu) * rs * gb.w + eb.w)};
        pkv[t2] = __builtin_convertvector(cat, bf16x8);
      }
    }

    // ---- GEMM3 ----
#pragma unroll
    for (int t = 0; t < 8; ++t) acc[t] = (f32x4){0.f, 0.f, 0.f, 0.f};
#pragma unroll
    for (int s = 0; s < 4; ++s) {
#pragma unroll
      for (int t = 0; t < 8; ++t) {
        bf16x8 af = w3pk[(t * 4 + s) * 64 + lane];
        acc[t] = __builtin_amdgcn_mfma_f32_16x16x32_bf16(af, pkv[s], acc[t], 0, 0, 0);
      }
    }

    // ---- final: +b3, tanh, store fp32 (dwordx4, nontemporal) ----
    {
      const float* pb = ppk + 6 * 128 + q * 32;
      float* orow = out + brow * 128 + q * 4;
#pragma unroll
      for (int t = 0; t < 8; ++t) {
        f32x4 bb = *(const f32x4*)(pb + t * 4);
        f32x4 v = acc[t];
        f32x4 o = {ftanh(v.x + bb.x), ftanh(v.y + bb.y),
                   ftanh(v.z + bb.z), ftanh(v.w + bb.w)};
        __builtin_nontemporal_store(o, (f32x4*)(orow + t * 16));
      }
    }
  }
#undef LOAD_BATCH
}

extern "C" void kernel_launch(void* const* d_in, const int* in_sizes, int n_in,
                              void* d_out, int out_size, void* d_ws, size_t ws_size,
                              hipStream_t stream) {
  const float* obs = (const float*)d_in[0];
  const float* w1  = (const float*)d_in[1];
  const float* b1  = (const float*)d_in[2];
  const float* g1  = (const float*)d_in[3];
  const float* be1 = (const float*)d_in[4];
  const float* w2  = (const float*)d_in[5];
  const float* b2  = (const float*)d_in[6];
  const float* g2  = (const float*)d_in[7];
  const float* be2 = (const float*)d_in[8];
  const float* w3  = (const float*)d_in[9];
  const float* b3  = (const float*)d_in[10];

  unsigned short* w1pk = (unsigned short*)d_ws;
  unsigned short* w2pk = w1pk + 65536;
  unsigned short* w3pk = w2pk + 16384;
  float*          ppk  = (float*)(w3pk + 16384);

  pack_kernel<<<388, 256, 0, stream>>>(w1, w2, w3, b1, g1, be1, b2, g2, be2, b3,
                                       w1pk, w2pk, w3pk, ppk);

  // 512 blocks x 512 thr; each block = 4 chunks x 128 rows (persistent-style)
  backbone_main<<<512, 512, 0, stream>>>(obs, (const unsigned char*)w1pk,
                                         (const bf16x8*)w2pk, (const bf16x8*)w3pk,
                                         ppk, (float*)d_out);
}

// Round 5
// 200.516 us; speedup vs baseline: 6.3734x; 6.3734x over previous
//
#include <hip/hip_runtime.h>
#include <hip/hip_bf16.h>

typedef __attribute__((ext_vector_type(8))) __bf16 bf16x8;
typedef __attribute__((ext_vector_type(4))) float f32x4;
typedef __attribute__((ext_vector_type(8))) float f32x8;

static __device__ __forceinline__ unsigned short bf16r(float f) {
  unsigned u = __builtin_bit_cast(unsigned, f);
  return (unsigned short)((u + 0x7FFFu + ((u >> 16) & 1u)) >> 16);
}

// tanh(x) = 1 - 2/(exp2(x*2*log2e)+1); saturates correctly for |x| large.
static __device__ __forceinline__ float ftanh(float x) {
  float e = __builtin_amdgcn_exp2f(x * 2.8853900817779268f);
  return 1.0f - 2.0f * __builtin_amdgcn_rcpf(e + 1.0f);
}

// global->LDS direct copy, 16B per lane (dest = wave-uniform base + lane*16,
// global src is PER-LANE -> swizzle applied on the source address)
static __device__ __forceinline__ void gload_lds16(const void* g, void* l) {
  __builtin_amdgcn_global_load_lds(
      (const __attribute__((address_space(1))) unsigned int*)g,
      (__attribute__((address_space(3))) unsigned int*)l, 16, 0, 0);
}

// ---------------- prologue: pack weights (bf16, frag order) + params --------
// ws layout (bytes):
//   w1pk: [0, 131072)          8 mtiles x 16 ksteps x 64 lanes x 8 bf16 (IDENTITY k)
//   w2pk: [131072, 163840)     8 mtiles x 4 ksteps x 64 lanes x 8 bf16 (pi-permuted k)
//   w3pk: [163840, 196608)     same as w2pk
//   ppk : [196608, 200192)     7 params x [q=4][32] f32
// w1 identity k-order: LDS-staged obs gives lane (q,rl) floats [q*8, q*8+8)
// of each 32-float kstep (chunks {2q,2q+1} of the 128B row segment).
__global__ void pack_kernel(const float* __restrict__ w1, const float* __restrict__ w2,
                            const float* __restrict__ w3, const float* __restrict__ b1,
                            const float* __restrict__ g1, const float* __restrict__ be1,
                            const float* __restrict__ b2, const float* __restrict__ g2,
                            const float* __restrict__ be2, const float* __restrict__ b3,
                            unsigned short* __restrict__ w1pk, unsigned short* __restrict__ w2pk,
                            unsigned short* __restrict__ w3pk, float* __restrict__ ppk) {
  int idx = blockIdx.x * 256 + threadIdx.x;
  if (idx < 65536) {            // w1, identity k-order
    int j = idx & 7, l = (idx >> 3) & 63, s = (idx >> 9) & 15, t = idx >> 13;
    int row = t * 16 + (l & 15);
    int col = s * 32 + (l >> 4) * 8 + j;
    w1pk[idx] = bf16r(w1[row * 512 + col]);
  } else if (idx < 81920) {     // w2, pi-permuted k-order
    int i = idx - 65536;
    int j = i & 7, l = (i >> 3) & 63, s = (i >> 9) & 3, t = i >> 11;
    int row = t * 16 + (l & 15);
    int col = (2 * s + (j >> 2)) * 16 + (l >> 4) * 4 + (j & 3);
    w2pk[i] = bf16r(w2[row * 128 + col]);
  } else if (idx < 98304) {     // w3, pi-permuted k-order
    int i = idx - 81920;
    int j = i & 7, l = (i >> 3) & 63, s = (i >> 9) & 3, t = i >> 11;
    int row = t * 16 + (l & 15);
    int col = (2 * s + (j >> 2)) * 16 + (l >> 4) * 4 + (j & 3);
    w3pk[i] = bf16r(w3[row * 128 + col]);
  } else if (idx < 99200) {     // params: b1,g1,be1,b2,g2,be2,b3
    int i = idx - 98304;        // 0..895
    int p = i >> 7;
    int r = i & 127;
    int qq = r >> 5, ii = r & 31;
    int m = (ii >> 2) * 16 + qq * 4 + (ii & 3);
    const float* src = (p == 0) ? b1 : (p == 1) ? g1 : (p == 2) ? be1
                     : (p == 3) ? b2 : (p == 4) ? g2 : (p == 5) ? be2 : b3;
    ppk[i] = src[m];
  }
}

// ---------------- fused backbone: baseline + full-line LDS obs staging ------
// R16. Unified model from R12(null)/R13(-10%)/R14(-5%)/R15(spills, but FETCH
// ~= 2x obs even with nt): nt loads issue 64B requests (frag layout caps
// per-row coverage at 4 lanes x 16B); HBM granule is 128B -> every obs line
// fetched twice. 537*2+134 = 1.21GB ~= 188us (2% match). R13's cached fix
// throttled on L1; R14's gload fix was right but paid w1-half refills +
// 2-deep ring + pinned segments. R16 = minimal graft onto the 188 baseline:
//  - w1 full 128KB resident (baseline fill, ONE barrier, no refill)
//  - per-wave 1-slot obs stage (16 waves x 2KB = 32KB; LDS = 160KB total)
//  - per kstep: vmcnt(0) [only obs gloads ever in flight], 2x ds_read_b128
//    (XOR-swizzled, verified in R14), lgkmcnt(0), issue next kstep's 2
//    full-128B-line gloads, 8 MFMAs.
// Little's law: 16 waves x 2KB per ~900cy = 87 GB/s/CU >> 24.6 fair share ->
// per-wave stalls don't de-saturate HBM. Predicted 115-135us; ~190 kills the
// request/granularity family for good.
__global__ __launch_bounds__(1024)
__attribute__((amdgpu_waves_per_eu(4, 4)))
void backbone_main(const float* __restrict__ obs,
                   const unsigned char* __restrict__ w1pk_g,
                   const bf16x8* __restrict__ w2pk,
                   const bf16x8* __restrict__ w3pk,
                   const float* __restrict__ ppk,
                   float* __restrict__ out) {
  __shared__ __align__(16) unsigned char lds[163840];

  const int tid  = threadIdx.x;
  const int lane = tid & 63;
  const int wv   = tid >> 6;          // 0..15
  const int q    = lane >> 4;
  const int rl   = lane & 15;
  const int l8   = lane >> 3;         // gload: row-sub 0..7
  const int c8   = lane & 7;          // gload: 16B chunk 0..7 within 128B
  const unsigned rowR = blockIdx.x * 256 + wv * 16;
  const size_t brow = (size_t)rowR + (unsigned)rl;

  // per-lane global src base: row rowR+l8, swizzled chunk (c8 ^ l8)
  const unsigned char* gsrc = (const unsigned char*)obs
      + ((size_t)rowR + (unsigned)l8) * 2048 + (unsigned)((c8 ^ l8) * 16);
  unsigned char* slot = lds + 131072 + wv * 2048;   // 1 slot: 16 rows x 128B

  // ds_read offsets: row rl, logical chunks {2q, 2q+1}, phys = j ^ (rl&7)
  const unsigned rd0 = (unsigned)(rl * 128 + ((2 * q) ^ (rl & 7)) * 16);
  const unsigned rd1 = (unsigned)(rl * 128 + ((2 * q + 1) ^ (rl & 7)) * 16);

  // ---- prologue: obs kstep 0 into the slot (HBM starts first) ----
  gload_lds16(gsrc,         slot);
  gload_lds16(gsrc + 16384, slot + 1024);
  // w1 fill (baseline pattern): 8 rounds x (1024 threads x 16B) = 128KB
#pragma unroll
  for (int r = 0; r < 8; ++r) {
    gload_lds16(w1pk_g + r * 16384 + tid * 16, lds + r * 16384 + wv * 1024);
  }
  __syncthreads();   // the only barrier; drains all vmcnt

  const bf16x8* w1l = (const bf16x8*)lds;   // frag (t,s): [(t*16+s)*64 + lane]

  f32x4 acc[8];
#pragma unroll
  for (int t = 0; t < 8; ++t) acc[t] = (f32x4){0.f, 0.f, 0.f, 0.f};

  // Per kstep s: wait own gloads (vmcnt(0); obs gloads are the only vmem in
  // flight), ds_read frags, drain lgkm, re-issue slot for kstep s+1, 8 MFMAs.
#define KSTEP(s)                                                                 \
  {                                                                              \
    asm volatile("s_waitcnt vmcnt(0)" ::: "memory");                             \
    __builtin_amdgcn_sched_barrier(0);                                           \
    f32x4 r0 = *(const f32x4*)(slot + rd0);                                      \
    f32x4 r1 = *(const f32x4*)(slot + rd1);                                      \
    asm volatile("s_waitcnt lgkmcnt(0)" ::: "memory");                           \
    __builtin_amdgcn_sched_barrier(0);                                           \
    if ((s) < 15) {                                                              \
      gload_lds16(gsrc + ((s) + 1) * 128,         slot);                         \
      gload_lds16(gsrc + ((s) + 1) * 128 + 16384, slot + 1024);                  \
    }                                                                            \
    f32x8 rr = {r0.x, r0.y, r0.z, r0.w, r1.x, r1.y, r1.z, r1.w};                 \
    bf16x8 bfrag = __builtin_convertvector(rr, bf16x8);                          \
    _Pragma("unroll")                                                            \
    for (int t = 0; t < 8; ++t) {                                                \
      bf16x8 af = w1l[(t * 16 + (s)) * 64 + lane];                               \
      acc[t] = __builtin_amdgcn_mfma_f32_16x16x32_bf16(af, bfrag, acc[t], 0, 0, 0); \
    }                                                                            \
  }

  KSTEP(0)  KSTEP(1)  KSTEP(2)  KSTEP(3)
  KSTEP(4)  KSTEP(5)  KSTEP(6)  KSTEP(7)
  KSTEP(8)  KSTEP(9)  KSTEP(10) KSTEP(11)
  KSTEP(12) KSTEP(13) KSTEP(14) KSTEP(15)
#undef KSTEP

  bf16x8 pkv[4];

  // ---- epilogue 1: +b1, LayerNorm(g1,be1), tanh, pack bf16 ----
  {
    const float* pb = ppk + 0 * 128 + q * 32;
    const float* pg = ppk + 1 * 128 + q * 32;
    const float* pe = ppk + 2 * 128 + q * 32;
    float s1 = 0.f, s2 = 0.f;
#pragma unroll
    for (int t = 0; t < 8; ++t) {
      f32x4 bb = *(const f32x4*)(pb + t * 4);
      f32x4 v = acc[t];
      v.x += bb.x; v.y += bb.y; v.z += bb.z; v.w += bb.w;
      acc[t] = v;
      s1 += (v.x + v.y) + (v.z + v.w);
      s2 += (v.x * v.x + v.y * v.y) + (v.z * v.z + v.w * v.w);
    }
    s1 += __shfl_xor(s1, 16, 64);
    s1 += __shfl_xor(s1, 32, 64);
    s2 += __shfl_xor(s2, 16, 64);
    s2 += __shfl_xor(s2, 32, 64);
    float mu  = s1 * (1.0f / 128.0f);
    float var = s2 * (1.0f / 128.0f) - mu * mu;
    float rs  = __builtin_amdgcn_rsqf(var + 1e-5f);
#pragma unroll
    for (int t2 = 0; t2 < 4; ++t2) {
      f32x4 ga = *(const f32x4*)(pg + (2 * t2) * 4);
      f32x4 gb = *(const f32x4*)(pg + (2 * t2 + 1) * 4);
      f32x4 ea = *(const f32x4*)(pe + (2 * t2) * 4);
      f32x4 eb = *(const f32x4*)(pe + (2 * t2 + 1) * 4);
      f32x4 va = acc[2 * t2];
      f32x4 vb = acc[2 * t2 + 1];
      f32x8 cat = {ftanh((va.x - mu) * rs * ga.x + ea.x),
                   ftanh((va.y - mu) * rs * ga.y + ea.y),
                   ftanh((va.z - mu) * rs * ga.z + ea.z),
                   ftanh((va.w - mu) * rs * ga.w + ea.w),
                   ftanh((vb.x - mu) * rs * gb.x + eb.x),
                   ftanh((vb.y - mu) * rs * gb.y + eb.y),
                   ftanh((vb.z - mu) * rs * gb.z + eb.z),
                   ftanh((vb.w - mu) * rs * gb.w + eb.w)};
      pkv[t2] = __builtin_convertvector(cat, bf16x8);
    }
  }

  // ---- GEMM2: K=128 (4 ksteps), B-frags are the lane's own pkv regs ----
#pragma unroll
  for (int t = 0; t < 8; ++t) acc[t] = (f32x4){0.f, 0.f, 0.f, 0.f};
#pragma unroll
  for (int s = 0; s < 4; ++s) {
#pragma unroll
    for (int t = 0; t < 8; ++t) {
      bf16x8 af = w2pk[(t * 4 + s) * 64 + lane];
      acc[t] = __builtin_amdgcn_mfma_f32_16x16x32_bf16(af, pkv[s], acc[t], 0, 0, 0);
    }
  }

  // ---- epilogue 2: +b2, LayerNorm(g2,be2), tanh, pack ----
  {
    const float* pb = ppk + 3 * 128 + q * 32;
    const float* pg = ppk + 4 * 128 + q * 32;
    const float* pe = ppk + 5 * 128 + q * 32;
    float s1 = 0.f, s2 = 0.f;
#pragma unroll
    for (int t = 0; t < 8; ++t) {
      f32x4 bb = *(const f32x4*)(pb + t * 4);
      f32x4 v = acc[t];
      v.x += bb.x; v.y += bb.y; v.z += bb.z; v.w += bb.w;
      acc[t] = v;
      s1 += (v.x + v.y) + (v.z + v.w);
      s2 += (v.x * v.x + v.y * v.y) + (v.z * v.z + v.w * v.w);
    }
    s1 += __shfl_xor(s1, 16, 64);
    s1 += __shfl_xor(s1, 32, 64);
    s2 += __shfl_xor(s2, 16, 64);
    s2 += __shfl_xor(s2, 32, 64);
    float mu  = s1 * (1.0f / 128.0f);
    float var = s2 * (1.0f / 128.0f) - mu * mu;
    float rs  = __builtin_amdgcn_rsqf(var + 1e-5f);
#pragma unroll
    for (int t2 = 0; t2 < 4; ++t2) {
      f32x4 ga = *(const f32x4*)(pg + (2 * t2) * 4);
      f32x4 gb = *(const f32x4*)(pg + (2 * t2 + 1) * 4);
      f32x4 ea = *(const f32x4*)(pe + (2 * t2) * 4);
      f32x4 eb = *(const f32x4*)(pe + (2 * t2 + 1) * 4);
      f32x4 va = acc[2 * t2];
      f32x4 vb = acc[2 * t2 + 1];
      f32x8 cat = {ftanh((va.x - mu) * rs * ga.x + ea.x),
                   ftanh((va.y - mu) * rs * ga.y + ea.y),
                   ftanh((va.z - mu) * rs * ga.z + ea.z),
                   ftanh((va.w - mu) * rs * ga.w + ea.w),
                   ftanh((vb.x - mu) * rs * gb.x + eb.x),
                   ftanh((vb.y - mu) * rs * gb.y + eb.y),
                   ftanh((vb.z - mu) * rs * gb.z + eb.z),
                   ftanh((vb.w - mu) * rs * gb.w + eb.w)};
      pkv[t2] = __builtin_convertvector(cat, bf16x8);
    }
  }

  // ---- GEMM3 ----
#pragma unroll
  for (int t = 0; t < 8; ++t) acc[t] = (f32x4){0.f, 0.f, 0.f, 0.f};
#pragma unroll
  for (int s = 0; s < 4; ++s) {
#pragma unroll
    for (int t = 0; t < 8; ++t) {
      bf16x8 af = w3pk[(t * 4 + s) * 64 + lane];
      acc[t] = __builtin_amdgcn_mfma_f32_16x16x32_bf16(af, pkv[s], acc[t], 0, 0, 0);
    }
  }

  // ---- final: +b3, tanh, store fp32 (dwordx4, nontemporal) ----
  {
    const float* pb = ppk + 6 * 128 + q * 32;
    float* orow = out + brow * 128 + q * 4;
#pragma unroll
    for (int t = 0; t < 8; ++t) {
      f32x4 bb = *(const f32x4*)(pb + t * 4);
      f32x4 v = acc[t];
      f32x4 o = {ftanh(v.x + bb.x), ftanh(v.y + bb.y),
                 ftanh(v.z + bb.z), ftanh(v.w + bb.w)};
      __builtin_nontemporal_store(o, (f32x4*)(orow + t * 16));
    }
  }
}

extern "C" void kernel_launch(void* const* d_in, const int* in_sizes, int n_in,
                              void* d_out, int out_size, void* d_ws, size_t ws_size,
                              hipStream_t stream) {
  const float* obs = (const float*)d_in[0];
  const float* w1  = (const float*)d_in[1];
  const float* b1  = (const float*)d_in[2];
  const float* g1  = (const float*)d_in[3];
  const float* be1 = (const float*)d_in[4];
  const float* w2  = (const float*)d_in[5];
  const float* b2  = (const float*)d_in[6];
  const float* g2  = (const float*)d_in[7];
  const float* be2 = (const float*)d_in[8];
  const float* w3  = (const float*)d_in[9];
  const float* b3  = (const float*)d_in[10];

  unsigned short* w1pk = (unsigned short*)d_ws;
  unsigned short* w2pk = w1pk + 65536;
  unsigned short* w3pk = w2pk + 16384;
  float*          ppk  = (float*)(w3pk + 16384);

  pack_kernel<<<388, 256, 0, stream>>>(w1, w2, w3, b1, g1, be1, b2, g2, be2, b3,
                                       w1pk, w2pk, w3pk, ppk);

  // non-persistent: 1024 blocks x 1024 thr; each block = 256 rows
  backbone_main<<<1024, 1024, 0, stream>>>(obs, (const unsigned char*)w1pk,
                                           (const bf16x8*)w2pk, (const bf16x8*)w3pk,
                                           ppk, (float*)d_out);
}